// Round 1
// baseline (2360.982 us; speedup 1.0000x reference)
//
#include <hip/hip_runtime.h>

#define BT    8192   // B*T
#define DMODEL 1024
#define NH    16
#define HD    64
#define TSEQ  2048

// ---------------- GEMM: C[M,N] = A[M,K] @ W[K,N] + bias[N] ----------------
template<int BM, int BN, int BK>
__global__ __launch_bounds__(256)
void gemm_bias(const float* __restrict__ A, const float* __restrict__ W,
               const float* __restrict__ bias, float* __restrict__ C,
               int M, int N, int K) {
  __shared__ float As[BK][BM + 4];
  __shared__ float Ws[BK][BN + 4];
  const int bm = blockIdx.y * BM;
  const int bn = blockIdx.x * BN;
  const int tid = threadIdx.x;
  const int tr = tid / 16;   // 0..15
  const int tc = tid % 16;   // 0..15
  float acc[4][4] = {};
  for (int k0 = 0; k0 < K; k0 += BK) {
    // A tile: BM x BK
    #pragma unroll
    for (int i = 0; i < (BM * BK) / 256; ++i) {
      int idx = tid + i * 256;
      int r = idx / BK;
      int c = idx % BK;
      As[c][r] = A[(size_t)(bm + r) * K + k0 + c];
    }
    // W tile: BK x BN
    #pragma unroll
    for (int i = 0; i < (BK * BN) / 256; ++i) {
      int idx = tid + i * 256;
      int r = idx / BN;
      int c = idx % BN;
      Ws[r][c] = W[(size_t)(k0 + r) * N + bn + c];
    }
    __syncthreads();
    #pragma unroll
    for (int kk = 0; kk < BK; ++kk) {
      float a[4], w[4];
      #pragma unroll
      for (int i = 0; i < 4; ++i) a[i] = As[kk][tr * 4 + i];
      #pragma unroll
      for (int j = 0; j < 4; ++j) w[j] = Ws[kk][tc * 4 + j];
      #pragma unroll
      for (int i = 0; i < 4; ++i)
        #pragma unroll
        for (int j = 0; j < 4; ++j)
          acc[i][j] += a[i] * w[j];
    }
    __syncthreads();
  }
  #pragma unroll
  for (int i = 0; i < 4; ++i) {
    int r = bm + tr * 4 + i;
    #pragma unroll
    for (int j = 0; j < 4; ++j) {
      int c = bn + tc * 4 + j;
      C[(size_t)r * N + c] = acc[i][j] + bias[c];
    }
  }
}

// ---------------- Fused causal attention ----------------
// qkv: [BT, 3*DMODEL] (q cols 0..1023, k 1024..2047, v 2048..3071)
// out: [BT, DMODEL] head-concatenated
__global__ __launch_bounds__(256)
void attn_fused(const float* __restrict__ qkv, float* __restrict__ out) {
  const int qchunk = blockIdx.x & 7;   // T/256 = 8 chunks
  const int bh = blockIdx.x >> 3;      // 0..63
  const int h = bh & 15;
  const int b = bh >> 4;
  const int tid = threadIdx.x;
  const int qrow = qchunk * 256 + tid;

  const size_t qbase = ((size_t)b * TSEQ + qrow) * (3 * DMODEL) + h * HD;
  float q[HD], o[HD];
  #pragma unroll
  for (int d = 0; d < HD; ++d) { q[d] = qkv[qbase + d]; o[d] = 0.f; }
  float m = -1e30f, l = 0.f;

  __shared__ float Ks[32][HD];
  __shared__ float Vs[32][HD];

  const int kend = qchunk * 256 + 256;                  // keys needed by this block
  const size_t kvbase = (size_t)b * TSEQ * (3 * DMODEL) + DMODEL + h * HD;

  for (int k0 = 0; k0 < kend; k0 += 32) {
    __syncthreads();
    // stage 32 keys + values: 32*64 floats each = 512 float4 each half
    #pragma unroll
    for (int i = 0; i < 2; ++i) {
      int idx = tid + i * 256;        // 0..511
      int r = idx >> 4;               // 16 float4 per row
      int c4 = idx & 15;
      const float* ksrc = qkv + kvbase + (size_t)(k0 + r) * (3 * DMODEL);
      ((float4*)&Ks[r][0])[c4] = reinterpret_cast<const float4*>(ksrc)[c4];
      ((float4*)&Vs[r][0])[c4] = reinterpret_cast<const float4*>(ksrc + DMODEL)[c4];
    }
    __syncthreads();
    int jmax = qrow - k0 + 1;
    if (jmax > 32) jmax = 32;
    for (int j = 0; j < jmax; ++j) {
      float s = 0.f;
      #pragma unroll
      for (int d = 0; d < HD; ++d) s += q[d] * Ks[j][d];
      s *= 0.125f;                    // 1/sqrt(64)
      if (s > m) {
        float corr = __expf(m - s);
        m = s;
        l *= corr;
        #pragma unroll
        for (int d = 0; d < HD; ++d) o[d] *= corr;
      }
      float p = __expf(s - m);
      l += p;
      #pragma unroll
      for (int d = 0; d < HD; ++d) o[d] += p * Vs[j][d];
    }
  }
  const float inv = 1.0f / l;
  float* op = out + ((size_t)b * TSEQ + qrow) * DMODEL + h * HD;
  #pragma unroll
  for (int d = 0; d < HD; ++d) op[d] = o[d] * inv;
}

extern "C" void kernel_launch(void* const* d_in, const int* in_sizes, int n_in,
                              void* d_out, int out_size, void* d_ws, size_t ws_size,
                              hipStream_t stream) {
  const float* x     = (const float*)d_in[0];
  const float* W_qkv = (const float*)d_in[1];
  const float* b_qkv = (const float*)d_in[2];
  const float* W_out = (const float*)d_in[3];
  const float* b_out = (const float*)d_in[4];
  float* out = (float*)d_out;

  float* qkv      = (float*)d_ws;                       // [8192, 3072]
  float* attn_out = qkv + (size_t)BT * (3 * DMODEL);    // [8192, 1024]

  dim3 blk(256);
  // QKV projection: M=8192, N=3072, K=1024
  gemm_bias<64, 64, 16><<<dim3(3 * DMODEL / 64, BT / 64), blk, 0, stream>>>(
      x, W_qkv, b_qkv, qkv, BT, 3 * DMODEL, DMODEL);
  // Fused causal attention
  attn_fused<<<dim3(64 * (TSEQ / 256)), blk, 0, stream>>>(qkv, attn_out);
  // Output projection: M=8192, N=1024, K=1024
  gemm_bias<64, 64, 16><<<dim3(DMODEL / 64, BT / 64), blk, 0, stream>>>(
      attn_out, W_out, b_out, out, BT, DMODEL, DMODEL);
}

// Round 2
// 270.252 us; speedup vs baseline: 8.7362x; 8.7362x over previous
//
#include <hip/hip_runtime.h>

#define BB 4
#define TT 2048
#define DD 1024
#define HH 16
#define HDIM 64
#define BT (BB*TT)       // 8192
#define D3 (3*DD)        // 3072

typedef __attribute__((ext_vector_type(8))) short bf16x8;
typedef __attribute__((ext_vector_type(4))) float f32x4;

__device__ __forceinline__ ushort f2bf(float f) {
  union { float f; uint32_t u; } v; v.f = f;
  uint32_t u = v.u + 0x7FFFu + ((v.u >> 16) & 1u);
  return (ushort)(u >> 16);
}

// ---------------- fp32 -> bf16 convert ----------------
__global__ __launch_bounds__(256)
void cvt_bf16(const float* __restrict__ in, ushort* __restrict__ out, int n4) {
  int i = blockIdx.x * blockDim.x + threadIdx.x;
  int stride = gridDim.x * blockDim.x;
  for (; i < n4; i += stride) {
    float4 v = ((const float4*)in)[i];
    ushort4 o;
    o.x = f2bf(v.x); o.y = f2bf(v.y); o.z = f2bf(v.z); o.w = f2bf(v.w);
    ((ushort4*)out)[i] = o;
  }
}

// ---------------- fp32 [K][N] -> bf16 transposed [N][K] ----------------
__global__ __launch_bounds__(256)
void transpose_cvt(const float* __restrict__ W, ushort* __restrict__ Wt, int K, int N) {
  __shared__ ushort Tt[64][68];
  const int n0 = blockIdx.x * 64;
  const int k0 = blockIdx.y * 64;
  const int tid = threadIdx.x;
  const int r = tid >> 4;
  const int c4 = (tid & 15) * 4;
  #pragma unroll
  for (int i = 0; i < 4; ++i) {
    int row = r + i * 16;   // k-local
    float4 v = *(const float4*)&W[(size_t)(k0 + row) * N + n0 + c4];
    Tt[c4 + 0][row] = f2bf(v.x);
    Tt[c4 + 1][row] = f2bf(v.y);
    Tt[c4 + 2][row] = f2bf(v.z);
    Tt[c4 + 3][row] = f2bf(v.w);
  }
  __syncthreads();
  #pragma unroll
  for (int i = 0; i < 4; ++i) {
    int row = r + i * 16;   // n-local
    ushort4 tv = *(const ushort4*)&Tt[row][c4];
    *(ushort4*)&Wt[(size_t)(n0 + row) * K + k0 + c4] = tv;
  }
}

// ---------------- bf16 MFMA GEMM: C[M,N] = A[M,1024] @ Wt[N,1024]^T + bias ----------------
// 128x128 tile, BK=64, 4 waves (2x2), each wave 64x64 out (4x4 frags of 16x16)
template<bool F32OUT>
__global__ __launch_bounds__(256)
void gemm_bt(const ushort* __restrict__ A, const ushort* __restrict__ Bw,
             const float* __restrict__ bias, void* __restrict__ C, int N) {
  __shared__ short As[128 * 72];
  __shared__ short Bs[128 * 72];
  const int tid = threadIdx.x;
  const int w = tid >> 6, lane = tid & 63;
  const int li = lane & 15, g = lane >> 4;
  const int wm = w >> 1, wn = w & 1;
  const int bm = blockIdx.y * 128;
  const int bn = blockIdx.x * 128;

  f32x4 acc[4][4] = {};

  for (int k0 = 0; k0 < 1024; k0 += 64) {
    __syncthreads();
    #pragma unroll
    for (int i = 0; i < 4; ++i) {
      int c = tid + i * 256;
      int row = c >> 3, kc = c & 7;
      uint4 va = *(const uint4*)(A + (size_t)(bm + row) * 1024 + k0 + kc * 8);
      *(uint4*)&As[row * 72 + kc * 8] = va;
      uint4 vb = *(const uint4*)(Bw + (size_t)(bn + row) * 1024 + k0 + kc * 8);
      *(uint4*)&Bs[row * 72 + kc * 8] = vb;
    }
    __syncthreads();
    #pragma unroll
    for (int c = 0; c < 2; ++c) {
      bf16x8 af[4], bfr[4];
      #pragma unroll
      for (int mi = 0; mi < 4; ++mi)
        af[mi] = *(bf16x8*)&As[(wm * 64 + mi * 16 + li) * 72 + c * 32 + g * 8];
      #pragma unroll
      for (int ni = 0; ni < 4; ++ni)
        bfr[ni] = *(bf16x8*)&Bs[(wn * 64 + ni * 16 + li) * 72 + c * 32 + g * 8];
      #pragma unroll
      for (int mi = 0; mi < 4; ++mi)
        #pragma unroll
        for (int ni = 0; ni < 4; ++ni)
          acc[mi][ni] = __builtin_amdgcn_mfma_f32_16x16x32_bf16(af[mi], bfr[ni], acc[mi][ni], 0, 0, 0);
    }
  }
  #pragma unroll
  for (int ni = 0; ni < 4; ++ni) {
    int col = bn + wn * 64 + ni * 16 + li;
    float bv = bias[col];
    #pragma unroll
    for (int mi = 0; mi < 4; ++mi) {
      int row = bm + wm * 64 + mi * 16 + g * 4;
      #pragma unroll
      for (int r = 0; r < 4; ++r) {
        float v = acc[mi][ni][r] + bv;
        if (F32OUT) ((float*)C)[(size_t)(row + r) * N + col] = v;
        else        ((ushort*)C)[(size_t)(row + r) * N + col] = f2bf(v);
      }
    }
  }
}

// ---------------- MFMA flash attention ----------------
// qkv bf16 [BT][3072]; out bf16 [BT][1024]
// block: 4 waves, 64 q-rows; K/V tiles of 64 keys staged in LDS
__global__ __launch_bounds__(256)
void attn_mfma(const ushort* __restrict__ qkv, ushort* __restrict__ out) {
  __shared__ short Ks[64 * 72];      // [key][hd], pad 8
  __shared__ short Vt[64 * 72];      // [hd][key], pad 8 (transposed)
  __shared__ short Pl[4][16 * 72];   // per-wave P^T as [q][key], pad 8

  const int bx = blockIdx.x;
  const int qt = (TT / 64 - 1) - (bx & 31);   // heavy tiles first
  const int bh = bx >> 5;
  const int h = bh & 15, b = bh >> 4;
  const int tid = threadIdx.x;
  const int w = tid >> 6;
  const int lane = tid & 63;
  const int li = lane & 15, g = lane >> 4;

  const int q0 = qt * 64;
  const int qg = q0 + w * 16 + li;

  const ushort* qrow = qkv + (size_t)(b * TT + qg) * D3 + h * HDIM;
  bf16x8 qf0 = *(const bf16x8*)(qrow + g * 8);
  bf16x8 qf1 = *(const bf16x8*)(qrow + 32 + g * 8);

  f32x4 o[4] = {};
  float m = -1e30f, lsum = 0.f;

  short* Plw = &Pl[w][0];
  const ushort* kbase = qkv + (size_t)(b * TT) * D3 + DD + h * HDIM;
  const ushort* vbase = qkv + (size_t)(b * TT) * D3 + 2 * DD + h * HDIM;

  const int nt = qt + 1;
  for (int it = 0; it < nt; ++it) {
    const int k0 = it * 64;
    __syncthreads();
    // stage K rows: 64 keys x 128B = 512 x 16B chunks
    #pragma unroll
    for (int i = 0; i < 2; ++i) {
      int c = tid + i * 256;
      int row = c >> 3, kc = c & 7;
      uint4 v = *(const uint4*)(kbase + (size_t)(k0 + row) * D3 + kc * 8);
      *(uint4*)&Ks[row * 72 + kc * 8] = v;
    }
    // stage V transposed: thread handles 8 d x 2 keys
    {
      int d0 = (tid >> 5) * 8;
      int kp = tid & 31;
      const ushort* v0p = vbase + (size_t)(k0 + 2 * kp) * D3 + d0;
      uint4 a = *(const uint4*)v0p;
      uint4 bb = *(const uint4*)(v0p + D3);
      const ushort* pa = (const ushort*)&a;
      const ushort* pb = (const ushort*)&bb;
      #pragma unroll
      for (int j = 0; j < 8; ++j) {
        uint32_t pk = (uint32_t)pa[j] | ((uint32_t)pb[j] << 16);
        *(uint32_t*)&Vt[(d0 + j) * 72 + 2 * kp] = pk;
      }
    }
    __syncthreads();

    // QK^T (swapped): S^T[key][q], q = li
    f32x4 s4[4];
    #pragma unroll
    for (int kt = 0; kt < 4; ++kt) {
      f32x4 acc = {0.f, 0.f, 0.f, 0.f};
      bf16x8 kf0 = *(bf16x8*)&Ks[(kt * 16 + li) * 72 + g * 8];
      bf16x8 kf1 = *(bf16x8*)&Ks[(kt * 16 + li) * 72 + 32 + g * 8];
      acc = __builtin_amdgcn_mfma_f32_16x16x32_bf16(kf0, qf0, acc, 0, 0, 0);
      acc = __builtin_amdgcn_mfma_f32_16x16x32_bf16(kf1, qf1, acc, 0, 0, 0);
      s4[kt] = acc;
    }

    // scale + causal mask + online softmax (per lane: 16 keys for query li)
    float p[4][4];
    float mt = -1e30f;
    #pragma unroll
    for (int kt = 0; kt < 4; ++kt)
      #pragma unroll
      for (int r = 0; r < 4; ++r) {
        int key = k0 + kt * 16 + g * 4 + r;
        float sv = s4[kt][r] * 0.125f;
        if (key > qg) sv = -1e30f;
        p[kt][r] = sv;
        mt = fmaxf(mt, sv);
      }
    mt = fmaxf(mt, __shfl_xor(mt, 16));
    mt = fmaxf(mt, __shfl_xor(mt, 32));
    float mn = fmaxf(m, mt);
    float corr = __expf(m - mn);
    float ls = 0.f;
    #pragma unroll
    for (int kt = 0; kt < 4; ++kt)
      #pragma unroll
      for (int r = 0; r < 4; ++r) {
        float pv = __expf(p[kt][r] - mn);
        p[kt][r] = pv;
        ls += pv;
      }
    ls += __shfl_xor(ls, 16);
    ls += __shfl_xor(ls, 32);
    lsum = lsum * corr + ls;
    m = mn;
    #pragma unroll
    for (int dt = 0; dt < 4; ++dt) {
      o[dt][0] *= corr; o[dt][1] *= corr; o[dt][2] *= corr; o[dt][3] *= corr;
    }

    // P^T -> LDS as [q=li][key], bf16
    #pragma unroll
    for (int kt = 0; kt < 4; ++kt) {
      uint32_t lo = (uint32_t)f2bf(p[kt][0]) | ((uint32_t)f2bf(p[kt][1]) << 16);
      uint32_t hi = (uint32_t)f2bf(p[kt][2]) | ((uint32_t)f2bf(p[kt][3]) << 16);
      *(uint32_t*)&Plw[li * 72 + kt * 16 + g * 4]     = lo;
      *(uint32_t*)&Plw[li * 72 + kt * 16 + g * 4 + 2] = hi;
    }

    // PV: O^T[d][q] += V^T frag x P^T frag
    bf16x8 pf0 = *(bf16x8*)&Plw[li * 72 + g * 8];
    bf16x8 pf1 = *(bf16x8*)&Plw[li * 72 + 32 + g * 8];
    #pragma unroll
    for (int dt = 0; dt < 4; ++dt) {
      bf16x8 vf0 = *(bf16x8*)&Vt[(dt * 16 + li) * 72 + g * 8];
      bf16x8 vf1 = *(bf16x8*)&Vt[(dt * 16 + li) * 72 + 32 + g * 8];
      o[dt] = __builtin_amdgcn_mfma_f32_16x16x32_bf16(vf0, pf0, o[dt], 0, 0, 0);
      o[dt] = __builtin_amdgcn_mfma_f32_16x16x32_bf16(vf1, pf1, o[dt], 0, 0, 0);
    }
  }

  const float inv = 1.f / lsum;
  ushort* orow = out + (size_t)(b * TT + qg) * DD + h * HDIM;
  #pragma unroll
  for (int dt = 0; dt < 4; ++dt)
    #pragma unroll
    for (int r = 0; r < 4; ++r)
      orow[dt * 16 + g * 4 + r] = f2bf(o[dt][r] * inv);
}

extern "C" void kernel_launch(void* const* d_in, const int* in_sizes, int n_in,
                              void* d_out, int out_size, void* d_ws, size_t ws_size,
                              hipStream_t stream) {
  const float* x     = (const float*)d_in[0];
  const float* W_qkv = (const float*)d_in[1];
  const float* b_qkv = (const float*)d_in[2];
  const float* W_out = (const float*)d_in[3];
  const float* b_out = (const float*)d_in[4];
  float* out = (float*)d_out;

  ushort* x_bf   = (ushort*)d_ws;                   // 8192*1024
  ushort* wtq    = x_bf + (size_t)BT * DD;          // 3072*1024
  ushort* wto    = wtq + (size_t)D3 * DD;           // 1024*1024
  ushort* qkv_bf = wto + (size_t)DD * DD;           // 8192*3072
  ushort* att_bf = qkv_bf + (size_t)BT * D3;        // 8192*1024

  cvt_bf16<<<2048, 256, 0, stream>>>(x, x_bf, BT * DD / 4);
  transpose_cvt<<<dim3(D3 / 64, DD / 64), 256, 0, stream>>>(W_qkv, wtq, DD, D3);
  transpose_cvt<<<dim3(DD / 64, DD / 64), 256, 0, stream>>>(W_out, wto, DD, DD);

  gemm_bt<false><<<dim3(D3 / 128, BT / 128), 256, 0, stream>>>(x_bf, wtq, b_qkv, (void*)qkv_bf, D3);
  attn_mfma<<<dim3(64 * (TT / 64)), 256, 0, stream>>>(qkv_bf, att_bf);
  gemm_bt<true><<<dim3(DD / 128, BT / 128), 256, 0, stream>>>(att_bf, wto, b_out, (void*)out, DD);
}

// Round 3
// 259.474 us; speedup vs baseline: 9.0991x; 1.0415x over previous
//
#include <hip/hip_runtime.h>
#include <hip/hip_bf16.h>

#define BB 4
#define TT 2048
#define DD 1024
#define HH 16
#define HDIM 64
#define BT (BB*TT)       // 8192
#define D3 (3*DD)        // 3072

typedef __attribute__((ext_vector_type(8))) short bf16x8;
typedef __attribute__((ext_vector_type(4))) float f32x4;

#if __has_builtin(__builtin_amdgcn_exp2f)
#define EXP2(x) __builtin_amdgcn_exp2f(x)
#else
#define EXP2(x) exp2f(x)
#endif

__device__ __forceinline__ ushort f2bf(float f) {
  union { float f; uint32_t u; } v; v.f = f;
  uint32_t u = v.u + 0x7FFFu + ((v.u >> 16) & 1u);
  return (ushort)(u >> 16);
}

__device__ __forceinline__ ushort f2bf_hw(float f) {
  __hip_bfloat16 h = __float2bfloat16(f);
  ushort u;
  __builtin_memcpy(&u, &h, 2);
  return u;
}

__device__ __forceinline__ float bf2f(ushort u) {
  union { uint32_t i; float f; } x; x.i = ((uint32_t)u) << 16; return x.f;
}

__device__ __forceinline__ void gload_lds16(const void* g, void* l) {
  __builtin_amdgcn_global_load_lds((const __attribute__((address_space(1))) void*)g,
                                   (__attribute__((address_space(3))) void*)l, 16, 0, 0);
}

// ---------------- fp32 -> bf16 convert ----------------
__global__ __launch_bounds__(256)
void cvt_bf16(const float* __restrict__ in, ushort* __restrict__ out, int n4) {
  int i = blockIdx.x * blockDim.x + threadIdx.x;
  int stride = gridDim.x * blockDim.x;
  for (; i < n4; i += stride) {
    float4 v = ((const float4*)in)[i];
    ushort4 o;
    o.x = f2bf(v.x); o.y = f2bf(v.y); o.z = f2bf(v.z); o.w = f2bf(v.w);
    ((ushort4*)out)[i] = o;
  }
}

// ---------------- fp32 [K][N] -> bf16 transposed [N][K] ----------------
__global__ __launch_bounds__(256)
void transpose_cvt(const float* __restrict__ W, ushort* __restrict__ Wt, int K, int N) {
  __shared__ ushort Tt[64][68];
  const int n0 = blockIdx.x * 64;
  const int k0 = blockIdx.y * 64;
  const int tid = threadIdx.x;
  const int r = tid >> 4;
  const int c4 = (tid & 15) * 4;
  #pragma unroll
  for (int i = 0; i < 4; ++i) {
    int row = r + i * 16;   // k-local
    float4 v = *(const float4*)&W[(size_t)(k0 + row) * N + n0 + c4];
    Tt[c4 + 0][row] = f2bf(v.x);
    Tt[c4 + 1][row] = f2bf(v.y);
    Tt[c4 + 2][row] = f2bf(v.z);
    Tt[c4 + 3][row] = f2bf(v.w);
  }
  __syncthreads();
  #pragma unroll
  for (int i = 0; i < 4; ++i) {
    int row = r + i * 16;   // n-local
    ushort4 tv = *(const ushort4*)&Tt[row][c4];
    *(ushort4*)&Wt[(size_t)(n0 + row) * K + k0 + c4] = tv;
  }
}

// ---------------- bf16 MFMA GEMM (m97 structure): C = A[M,1024] @ Wt[N,1024]^T + bias ----------------
// 128x128 tile, BK=64, 4 waves (2x2), global_load_lds staging, linear LDS
template<bool F32OUT>
__global__ __launch_bounds__(256)
void gemm_bt(const ushort* __restrict__ A, const ushort* __restrict__ Bw,
             const float* __restrict__ bias, void* __restrict__ C, int N) {
  __shared__ __align__(16) short As[128 * 64];
  __shared__ __align__(16) short Bs[128 * 64];
  const int tid = threadIdx.x;
  const int w = tid >> 6, lane = tid & 63;
  const int li = lane & 15, g = lane >> 4;
  const int wm = w >> 1, wn = w & 1;
  const int bm = blockIdx.y * 128;
  const int bn = blockIdx.x * 128;
  const int lrow = lane >> 3;      // 0..7
  const int lchunk = lane & 7;

  f32x4 acc[4][4] = {};

  for (int k0 = 0; k0 < 1024; k0 += 64) {
    __syncthreads();
    #pragma unroll
    for (int j = 0; j < 4; ++j) {
      int row = j * 32 + w * 8 + lrow;
      gload_lds16(A  + (size_t)(bm + row) * 1024 + k0 + lchunk * 8, As + j * 2048 + w * 512);
      gload_lds16(Bw + (size_t)(bn + row) * 1024 + k0 + lchunk * 8, Bs + j * 2048 + w * 512);
    }
    __syncthreads();
    #pragma unroll
    for (int c = 0; c < 2; ++c) {
      bf16x8 af[4], bfr[4];
      #pragma unroll
      for (int mi = 0; mi < 4; ++mi)
        af[mi] = *(bf16x8*)&As[(wm * 64 + mi * 16 + li) * 64 + c * 32 + g * 8];
      #pragma unroll
      for (int ni = 0; ni < 4; ++ni)
        bfr[ni] = *(bf16x8*)&Bs[(wn * 64 + ni * 16 + li) * 64 + c * 32 + g * 8];
      #pragma unroll
      for (int mi = 0; mi < 4; ++mi)
        #pragma unroll
        for (int ni = 0; ni < 4; ++ni)
          acc[mi][ni] = __builtin_amdgcn_mfma_f32_16x16x32_bf16(af[mi], bfr[ni], acc[mi][ni], 0, 0, 0);
    }
  }
  #pragma unroll
  for (int ni = 0; ni < 4; ++ni) {
    int col = bn + wn * 64 + ni * 16 + li;
    float bv = bias[col];
    #pragma unroll
    for (int mi = 0; mi < 4; ++mi) {
      int row = bm + wm * 64 + mi * 16 + g * 4;
      #pragma unroll
      for (int r = 0; r < 4; ++r) {
        float v = acc[mi][ni][r] + bv;
        if (F32OUT) ((float*)C)[(size_t)(row + r) * N + col] = v;
        else        ((ushort*)C)[(size_t)(row + r) * N + col] = f2bf_hw(v);
      }
    }
  }
}

// ---------------- MFMA flash attention ----------------
// 4 waves x 32 q-rows = 128 q/block; K/V tiles of 64; Q pre-scaled into log2 domain.
__global__ __launch_bounds__(256)
void attn_mfma(const ushort* __restrict__ qkv, ushort* __restrict__ out) {
  __shared__ __align__(16) short Ks[64 * 88];
  __shared__ __align__(16) short Vt[64 * 88];
  __shared__ __align__(16) short Pl[4][16 * 88];

  const int bx = blockIdx.x;
  const int qt = 15 - (bx & 15);          // heavy q-tiles first
  const int bh = bx >> 4;                 // 0..63
  const int h = bh & 15, b = bh >> 4;
  const int tid = threadIdx.x;
  const int w = tid >> 6;
  const int lane = tid & 63;
  const int li = lane & 15, g = lane >> 4;

  const int q0 = qt * 128;
  const int qg0 = q0 + w * 32;

  // Q frags, scaled by 1/sqrt(64) * log2(e)
  bf16x8 qfr[2][2];
  #pragma unroll
  for (int qf = 0; qf < 2; ++qf) {
    const ushort* qrow = qkv + (size_t)(b * TT + qg0 + qf * 16 + li) * D3 + h * HDIM;
    #pragma unroll
    for (int c = 0; c < 2; ++c) {
      uint4 raw = *(const uint4*)(qrow + c * 32 + g * 8);
      const ushort* rp = (const ushort*)&raw;
      bf16x8 v;
      #pragma unroll
      for (int j = 0; j < 8; ++j)
        v[j] = (short)f2bf_hw(bf2f(rp[j]) * 0.18033688f);
      qfr[qf][c] = v;
    }
  }

  f32x4 o[4][2] = {};
  float mreg[2] = {-1e30f, -1e30f};
  float lsum[2] = {0.f, 0.f};

  const ushort* kbase = qkv + (size_t)b * TT * D3 + DD + h * HDIM;
  const ushort* vbase = kbase + DD;

  const int krow0 = tid >> 3;     // 0..31
  const int kc = tid & 7;
  const int d0 = (tid >> 5) * 8;
  const int kp = tid & 31;

  const int nt = 2 * qt + 2;
  const int itlast = 2 * qt + (w >> 1);

  uint4 kpre0, kpre1, vpre0, vpre1;
  {
    const ushort* kg = kbase + (size_t)krow0 * D3 + kc * 8;
    kpre0 = *(const uint4*)kg;
    kpre1 = *(const uint4*)(kg + (size_t)32 * D3);
    const ushort* vg = vbase + (size_t)(2 * kp) * D3 + d0;
    vpre0 = *(const uint4*)vg;
    vpre1 = *(const uint4*)(vg + D3);
  }

  for (int it = 0; it < nt; ++it) {
    const int k0 = it * 64;
    // commit prefetched tile to LDS
    *(uint4*)&Ks[krow0 * 88 + kc * 8] = kpre0;
    *(uint4*)&Ks[(krow0 + 32) * 88 + kc * 8] = kpre1;
    {
      const ushort* pa = (const ushort*)&vpre0;
      const ushort* pb = (const ushort*)&vpre1;
      #pragma unroll
      for (int j = 0; j < 8; ++j) {
        uint32_t pk = (uint32_t)pa[j] | ((uint32_t)pb[j] << 16);
        *(uint32_t*)&Vt[(d0 + j) * 88 + 2 * kp] = pk;
      }
    }
    __syncthreads();
    // prefetch next tile (overlaps compute)
    if (it + 1 < nt) {
      const ushort* kg = kbase + (size_t)(k0 + 64 + krow0) * D3 + kc * 8;
      kpre0 = *(const uint4*)kg;
      kpre1 = *(const uint4*)(kg + (size_t)32 * D3);
      const ushort* vg = vbase + (size_t)(k0 + 64 + 2 * kp) * D3 + d0;
      vpre0 = *(const uint4*)vg;
      vpre1 = *(const uint4*)(vg + D3);
    }
    if (it <= itlast) {
      const bool domask = (it == itlast);
      bf16x8 pf[2][2];
      short* Plw = &Pl[w][0];
      #pragma unroll
      for (int qf = 0; qf < 2; ++qf) {
        f32x4 s[4];
        #pragma unroll
        for (int kt = 0; kt < 4; ++kt) {
          bf16x8 kf0 = *(bf16x8*)&Ks[(kt * 16 + li) * 88 + g * 8];
          bf16x8 kf1 = *(bf16x8*)&Ks[(kt * 16 + li) * 88 + 32 + g * 8];
          f32x4 a = {0.f, 0.f, 0.f, 0.f};
          a = __builtin_amdgcn_mfma_f32_16x16x32_bf16(kf0, qfr[qf][0], a, 0, 0, 0);
          a = __builtin_amdgcn_mfma_f32_16x16x32_bf16(kf1, qfr[qf][1], a, 0, 0, 0);
          s[kt] = a;
        }
        const int qrow = qg0 + qf * 16 + li;
        if (domask) {
          #pragma unroll
          for (int kt = 0; kt < 4; ++kt)
            #pragma unroll
            for (int r = 0; r < 4; ++r) {
              int key = k0 + kt * 16 + g * 4 + r;
              if (key > qrow) s[kt][r] = -1e30f;
            }
        }
        float mt = fmaxf(fmaxf(fmaxf(s[0][0], s[0][1]), fmaxf(s[0][2], s[0][3])),
                         fmaxf(fmaxf(s[1][0], s[1][1]), fmaxf(s[1][2], s[1][3])));
        mt = fmaxf(mt, fmaxf(fmaxf(fmaxf(s[2][0], s[2][1]), fmaxf(s[2][2], s[2][3])),
                             fmaxf(fmaxf(s[3][0], s[3][1]), fmaxf(s[3][2], s[3][3]))));
        mt = fmaxf(mt, __shfl_xor(mt, 16));
        mt = fmaxf(mt, __shfl_xor(mt, 32));
        if (__any(mt > mreg[qf] + 8.f)) {
          float mn = fmaxf(mreg[qf], mt);
          float corr = EXP2(mreg[qf] - mn);
          lsum[qf] *= corr;
          #pragma unroll
          for (int dt = 0; dt < 4; ++dt) {
            o[dt][qf][0] *= corr; o[dt][qf][1] *= corr;
            o[dt][qf][2] *= corr; o[dt][qf][3] *= corr;
          }
          mreg[qf] = mn;
        }
        const float mq = mreg[qf];
        float ls = 0.f;
        #pragma unroll
        for (int kt = 0; kt < 4; ++kt) {
          float p0 = EXP2(s[kt][0] - mq);
          float p1 = EXP2(s[kt][1] - mq);
          float p2 = EXP2(s[kt][2] - mq);
          float p3 = EXP2(s[kt][3] - mq);
          ls += (p0 + p1) + (p2 + p3);
          uint2 val;
          val.x = (uint32_t)f2bf_hw(p0) | ((uint32_t)f2bf_hw(p1) << 16);
          val.y = (uint32_t)f2bf_hw(p2) | ((uint32_t)f2bf_hw(p3) << 16);
          *(uint2*)&Plw[li * 88 + kt * 16 + g * 4] = val;
        }
        lsum[qf] += ls;
        pf[qf][0] = *(bf16x8*)&Plw[li * 88 + g * 8];
        pf[qf][1] = *(bf16x8*)&Plw[li * 88 + 32 + g * 8];
      }
      #pragma unroll
      for (int dt = 0; dt < 4; ++dt) {
        bf16x8 vf0 = *(bf16x8*)&Vt[(dt * 16 + li) * 88 + g * 8];
        bf16x8 vf1 = *(bf16x8*)&Vt[(dt * 16 + li) * 88 + 32 + g * 8];
        #pragma unroll
        for (int qf = 0; qf < 2; ++qf) {
          o[dt][qf] = __builtin_amdgcn_mfma_f32_16x16x32_bf16(vf0, pf[qf][0], o[dt][qf], 0, 0, 0);
          o[dt][qf] = __builtin_amdgcn_mfma_f32_16x16x32_bf16(vf1, pf[qf][1], o[dt][qf], 0, 0, 0);
        }
      }
    }
    __syncthreads();
  }

  #pragma unroll
  for (int qf = 0; qf < 2; ++qf) {
    float lt = lsum[qf];
    lt += __shfl_xor(lt, 16);
    lt += __shfl_xor(lt, 32);
    float inv = 1.f / lt;
    ushort* orow = out + (size_t)(b * TT + qg0 + qf * 16 + li) * DD + h * HDIM;
    #pragma unroll
    for (int dt = 0; dt < 4; ++dt)
      #pragma unroll
      for (int r = 0; r < 4; ++r)
        orow[dt * 16 + g * 4 + r] = f2bf_hw(o[dt][qf][r] * inv);
  }
}

extern "C" void kernel_launch(void* const* d_in, const int* in_sizes, int n_in,
                              void* d_out, int out_size, void* d_ws, size_t ws_size,
                              hipStream_t stream) {
  const float* x     = (const float*)d_in[0];
  const float* W_qkv = (const float*)d_in[1];
  const float* b_qkv = (const float*)d_in[2];
  const float* W_out = (const float*)d_in[3];
  const float* b_out = (const float*)d_in[4];
  float* out = (float*)d_out;

  ushort* x_bf   = (ushort*)d_ws;                   // 8192*1024
  ushort* wtq    = x_bf + (size_t)BT * DD;          // 3072*1024
  ushort* wto    = wtq + (size_t)D3 * DD;           // 1024*1024
  ushort* qkv_bf = wto + (size_t)DD * DD;           // 8192*3072
  ushort* att_bf = qkv_bf + (size_t)BT * D3;        // 8192*1024

  cvt_bf16<<<2048, 256, 0, stream>>>(x, x_bf, BT * DD / 4);
  transpose_cvt<<<dim3(D3 / 64, DD / 64), 256, 0, stream>>>(W_qkv, wtq, DD, D3);
  transpose_cvt<<<dim3(DD / 64, DD / 64), 256, 0, stream>>>(W_out, wto, DD, DD);

  gemm_bt<false><<<dim3(D3 / 128, BT / 128), 256, 0, stream>>>(x_bf, wtq, b_qkv, (void*)qkv_bf, D3);
  attn_mfma<<<dim3(64 * (TT / 128)), 256, 0, stream>>>(qkv_bf, att_bf);
  gemm_bt<true><<<dim3(DD / 128, BT / 128), 256, 0, stream>>>(att_bf, wto, b_out, (void*)out, DD);
}

// Round 4
// 229.762 us; speedup vs baseline: 10.2758x; 1.1293x over previous
//
#include <hip/hip_runtime.h>
#include <hip/hip_bf16.h>

#define BB 4
#define TT 2048
#define DD 1024
#define HH 16
#define HDIM 64
#define BT (BB*TT)       // 8192
#define D3 (3*DD)        // 3072

typedef __attribute__((ext_vector_type(8))) short bf16x8;
typedef __attribute__((ext_vector_type(4))) float f32x4;

#if __has_builtin(__builtin_amdgcn_exp2f)
#define EXP2(x) __builtin_amdgcn_exp2f(x)
#else
#define EXP2(x) exp2f(x)
#endif

__device__ __forceinline__ ushort f2bf(float f) {
  union { float f; uint32_t u; } v; v.f = f;
  uint32_t u = v.u + 0x7FFFu + ((v.u >> 16) & 1u);
  return (ushort)(u >> 16);
}

__device__ __forceinline__ ushort f2bf_hw(float f) {
  __hip_bfloat16 h = __float2bfloat16(f);
  ushort u;
  __builtin_memcpy(&u, &h, 2);
  return u;
}

__device__ __forceinline__ float bf2f(ushort u) {
  union { uint32_t i; float f; } x; x.i = ((uint32_t)u) << 16; return x.f;
}

__device__ __forceinline__ void gload_lds16(const void* g, void* l) {
  __builtin_amdgcn_global_load_lds((const __attribute__((address_space(1))) void*)g,
                                   (__attribute__((address_space(3))) void*)l, 16, 0, 0);
}

// ---------------- fp32 -> bf16 convert ----------------
__global__ __launch_bounds__(256)
void cvt_bf16(const float* __restrict__ in, ushort* __restrict__ out, int n4) {
  int i = blockIdx.x * blockDim.x + threadIdx.x;
  int stride = gridDim.x * blockDim.x;
  for (; i < n4; i += stride) {
    float4 v = ((const float4*)in)[i];
    ushort4 o;
    o.x = f2bf(v.x); o.y = f2bf(v.y); o.z = f2bf(v.z); o.w = f2bf(v.w);
    ((ushort4*)out)[i] = o;
  }
}

// ---------------- fp32 [K][N] -> bf16 transposed [N][K] ----------------
__global__ __launch_bounds__(256)
void transpose_cvt(const float* __restrict__ W, ushort* __restrict__ Wt, int K, int N) {
  __shared__ ushort Tt[64][68];
  const int n0 = blockIdx.x * 64;
  const int k0 = blockIdx.y * 64;
  const int tid = threadIdx.x;
  const int r = tid >> 4;
  const int c4 = (tid & 15) * 4;
  #pragma unroll
  for (int i = 0; i < 4; ++i) {
    int row = r + i * 16;   // k-local
    float4 v = *(const float4*)&W[(size_t)(k0 + row) * N + n0 + c4];
    Tt[c4 + 0][row] = f2bf(v.x);
    Tt[c4 + 1][row] = f2bf(v.y);
    Tt[c4 + 2][row] = f2bf(v.z);
    Tt[c4 + 3][row] = f2bf(v.w);
  }
  __syncthreads();
  #pragma unroll
  for (int i = 0; i < 4; ++i) {
    int row = r + i * 16;   // n-local
    ushort4 tv = *(const ushort4*)&Tt[row][c4];
    *(ushort4*)&Wt[(size_t)(n0 + row) * K + k0 + c4] = tv;
  }
}

// ---------------- bf16 MFMA GEMM (m97 structure): C = A[M,1024] @ Wt[N,1024]^T + bias ----------------
template<bool F32OUT>
__global__ __launch_bounds__(256)
void gemm_bt(const ushort* __restrict__ A, const ushort* __restrict__ Bw,
             const float* __restrict__ bias, void* __restrict__ C, int N) {
  __shared__ __align__(16) short As[128 * 64];
  __shared__ __align__(16) short Bs[128 * 64];
  const int tid = threadIdx.x;
  const int w = tid >> 6, lane = tid & 63;
  const int li = lane & 15, g = lane >> 4;
  const int wm = w >> 1, wn = w & 1;
  const int bm = blockIdx.y * 128;
  const int bn = blockIdx.x * 128;
  const int lrow = lane >> 3;      // 0..7
  const int lchunk = lane & 7;

  f32x4 acc[4][4] = {};

  for (int k0 = 0; k0 < 1024; k0 += 64) {
    __syncthreads();
    #pragma unroll
    for (int j = 0; j < 4; ++j) {
      int row = j * 32 + w * 8 + lrow;
      gload_lds16(A  + (size_t)(bm + row) * 1024 + k0 + lchunk * 8, As + j * 2048 + w * 512);
      gload_lds16(Bw + (size_t)(bn + row) * 1024 + k0 + lchunk * 8, Bs + j * 2048 + w * 512);
    }
    __syncthreads();
    #pragma unroll
    for (int c = 0; c < 2; ++c) {
      bf16x8 af[4], bfr[4];
      #pragma unroll
      for (int mi = 0; mi < 4; ++mi)
        af[mi] = *(bf16x8*)&As[(wm * 64 + mi * 16 + li) * 64 + c * 32 + g * 8];
      #pragma unroll
      for (int ni = 0; ni < 4; ++ni)
        bfr[ni] = *(bf16x8*)&Bs[(wn * 64 + ni * 16 + li) * 64 + c * 32 + g * 8];
      #pragma unroll
      for (int mi = 0; mi < 4; ++mi)
        #pragma unroll
        for (int ni = 0; ni < 4; ++ni)
          acc[mi][ni] = __builtin_amdgcn_mfma_f32_16x16x32_bf16(af[mi], bfr[ni], acc[mi][ni], 0, 0, 0);
    }
  }
  #pragma unroll
  for (int ni = 0; ni < 4; ++ni) {
    int col = bn + wn * 64 + ni * 16 + li;
    float bv = bias[col];
    #pragma unroll
    for (int mi = 0; mi < 4; ++mi) {
      int row = bm + wm * 64 + mi * 16 + g * 4;
      #pragma unroll
      for (int r = 0; r < 4; ++r) {
        float v = acc[mi][ni][r] + bv;
        if (F32OUT) ((float*)C)[(size_t)(row + r) * N + col] = v;
        else        ((ushort*)C)[(size_t)(row + r) * N + col] = f2bf_hw(v);
      }
    }
  }
}

// ---------------- MFMA flash attention ----------------
// 4 waves x 32 q-rows = 128 q/block; K/V tiles of 64; swizzled LDS; balanced qt map.
__global__ __launch_bounds__(256)
void attn_mfma(const ushort* __restrict__ qkv, ushort* __restrict__ out) {
  __shared__ __align__(16) short Ks[64 * 64];
  __shared__ __align__(16) short Vt[64 * 64];
  __shared__ __align__(16) short Pl[4 * 16 * 64];

  const int bx = blockIdx.x;
  // balanced (bh, qt) map: blocks that co-reside on a CU (bx ≡ r mod 256)
  // get qts {15-t, t, (7-t)&15, (t+8)&15} -> per-CU work sum constant.
  const int gi = bx >> 8;           // 0..3
  const int rr = bx & 255;
  const int t  = rr & 15;
  const int bh = gi * 16 + (rr >> 4);   // 0..63
  int qt;
  if      (gi == 0) qt = 15 - t;
  else if (gi == 1) qt = t;
  else if (gi == 2) qt = (7 - t) & 15;
  else              qt = (t + 8) & 15;

  const int h = bh & 15, b = bh >> 4;
  const int tid = threadIdx.x;
  const int w = tid >> 6;
  const int lane = tid & 63;
  const int li = lane & 15, g = lane >> 4;
  const int sw = (li & 7) << 4;     // XOR swizzle const for this lane's rows

  char* KsB = (char*)Ks;
  char* VtB = (char*)Vt;
  char* PlB = (char*)Pl + w * 2048;

  const int q0 = qt * 128;
  const int qg0 = q0 + w * 32;

  // Q frags, scaled by 1/sqrt(64) * log2(e)
  bf16x8 qfr[2][2];
  #pragma unroll
  for (int qf = 0; qf < 2; ++qf) {
    const ushort* qrow = qkv + (size_t)(b * TT + qg0 + qf * 16 + li) * D3 + h * HDIM;
    #pragma unroll
    for (int c = 0; c < 2; ++c) {
      uint4 raw = *(const uint4*)(qrow + c * 32 + g * 8);
      const ushort* rp = (const ushort*)&raw;
      bf16x8 v;
      #pragma unroll
      for (int j = 0; j < 8; ++j)
        v[j] = (short)f2bf_hw(bf2f(rp[j]) * 0.18033688f);
      qfr[qf][c] = v;
    }
  }

  f32x4 o[4][2] = {};
  float mreg[2] = {-1e30f, -1e30f};
  float lsum[2] = {0.f, 0.f};

  const ushort* kbase = qkv + (size_t)b * TT * D3 + DD + h * HDIM;
  const ushort* vbase = kbase + DD;

  const int krow0 = tid >> 3;     // 0..31
  const int kc = tid & 7;
  const int d0 = (tid >> 5) * 8;
  const int kp = tid & 31;

  const int nt = 2 * qt + 2;
  const int itlast = 2 * qt + (w >> 1);

  uint4 kpre0, kpre1, vpre0, vpre1;
  {
    const ushort* kg = kbase + (size_t)krow0 * D3 + kc * 8;
    kpre0 = *(const uint4*)kg;
    kpre1 = *(const uint4*)(kg + (size_t)32 * D3);
    const ushort* vg = vbase + (size_t)(2 * kp) * D3 + d0;
    vpre0 = *(const uint4*)vg;
    vpre1 = *(const uint4*)(vg + D3);
  }

  const int kswz = (kc * 16) ^ ((krow0 & 7) << 4);

  for (int it = 0; it < nt; ++it) {
    const int k0 = it * 64;
    // commit prefetched tile to LDS (swizzled rows)
    *(uint4*)(KsB + krow0 * 128 + kswz) = kpre0;
    *(uint4*)(KsB + (krow0 + 32) * 128 + kswz) = kpre1;
    {
      const ushort* pa = (const ushort*)&vpre0;
      const ushort* pb = (const ushort*)&vpre1;
      #pragma unroll
      for (int j = 0; j < 8; ++j) {
        uint32_t pk = (uint32_t)pa[j] | ((uint32_t)pb[j] << 16);
        *(uint32_t*)(VtB + (d0 + j) * 128 + ((4 * kp) ^ (j << 4))) = pk;
      }
    }
    __syncthreads();
    // prefetch next tile (overlaps compute)
    if (it + 1 < nt) {
      const ushort* kg = kbase + (size_t)(k0 + 64 + krow0) * D3 + kc * 8;
      kpre0 = *(const uint4*)kg;
      kpre1 = *(const uint4*)(kg + (size_t)32 * D3);
      const ushort* vg = vbase + (size_t)(k0 + 64 + 2 * kp) * D3 + d0;
      vpre0 = *(const uint4*)vg;
      vpre1 = *(const uint4*)(vg + D3);
    }
    if (it <= itlast) {
      const bool domask = (it == itlast);
      bf16x8 pf[2][2];
      #pragma unroll
      for (int qf = 0; qf < 2; ++qf) {
        f32x4 s[4];
        __builtin_amdgcn_s_setprio(1);
        #pragma unroll
        for (int kt = 0; kt < 4; ++kt) {
          const int row = kt * 16 + li;
          bf16x8 kf0 = *(bf16x8*)(KsB + row * 128 + ((g * 16) ^ sw));
          bf16x8 kf1 = *(bf16x8*)(KsB + row * 128 + ((64 + g * 16) ^ sw));
          f32x4 a = {0.f, 0.f, 0.f, 0.f};
          a = __builtin_amdgcn_mfma_f32_16x16x32_bf16(kf0, qfr[qf][0], a, 0, 0, 0);
          a = __builtin_amdgcn_mfma_f32_16x16x32_bf16(kf1, qfr[qf][1], a, 0, 0, 0);
          s[kt] = a;
        }
        __builtin_amdgcn_s_setprio(0);
        const int qrow = qg0 + qf * 16 + li;
        if (domask) {
          #pragma unroll
          for (int kt = 0; kt < 4; ++kt)
            #pragma unroll
            for (int r = 0; r < 4; ++r) {
              int key = k0 + kt * 16 + g * 4 + r;
              if (key > qrow) s[kt][r] = -1e30f;
            }
        }
        float mt = fmaxf(fmaxf(fmaxf(s[0][0], s[0][1]), fmaxf(s[0][2], s[0][3])),
                         fmaxf(fmaxf(s[1][0], s[1][1]), fmaxf(s[1][2], s[1][3])));
        mt = fmaxf(mt, fmaxf(fmaxf(fmaxf(s[2][0], s[2][1]), fmaxf(s[2][2], s[2][3])),
                             fmaxf(fmaxf(s[3][0], s[3][1]), fmaxf(s[3][2], s[3][3]))));
        mt = fmaxf(mt, __shfl_xor(mt, 16));
        mt = fmaxf(mt, __shfl_xor(mt, 32));
        if (__any(mt > mreg[qf] + 8.f)) {
          float mn = fmaxf(mreg[qf], mt);
          float corr = EXP2(mreg[qf] - mn);
          lsum[qf] *= corr;
          #pragma unroll
          for (int dt = 0; dt < 4; ++dt) {
            o[dt][qf][0] *= corr; o[dt][qf][1] *= corr;
            o[dt][qf][2] *= corr; o[dt][qf][3] *= corr;
          }
          mreg[qf] = mn;
        }
        const float mq = mreg[qf];
        float ls = 0.f;
        #pragma unroll
        for (int kt = 0; kt < 4; ++kt) {
          float p0 = EXP2(s[kt][0] - mq);
          float p1 = EXP2(s[kt][1] - mq);
          float p2 = EXP2(s[kt][2] - mq);
          float p3 = EXP2(s[kt][3] - mq);
          ls += (p0 + p1) + (p2 + p3);
          uint2 val;
          val.x = (uint32_t)f2bf_hw(p0) | ((uint32_t)f2bf_hw(p1) << 16);
          val.y = (uint32_t)f2bf_hw(p2) | ((uint32_t)f2bf_hw(p3) << 16);
          *(uint2*)(PlB + li * 128 + ((kt * 32 + g * 8) ^ sw)) = val;
        }
        lsum[qf] += ls;
        pf[qf][0] = *(bf16x8*)(PlB + li * 128 + ((g * 16) ^ sw));
        pf[qf][1] = *(bf16x8*)(PlB + li * 128 + ((64 + g * 16) ^ sw));
      }
      __builtin_amdgcn_s_setprio(1);
      #pragma unroll
      for (int dt = 0; dt < 4; ++dt) {
        const int vrow = dt * 16 + li;
        bf16x8 vf0 = *(bf16x8*)(VtB + vrow * 128 + ((g * 16) ^ sw));
        bf16x8 vf1 = *(bf16x8*)(VtB + vrow * 128 + ((64 + g * 16) ^ sw));
        #pragma unroll
        for (int qf = 0; qf < 2; ++qf) {
          o[dt][qf] = __builtin_amdgcn_mfma_f32_16x16x32_bf16(vf0, pf[qf][0], o[dt][qf], 0, 0, 0);
          o[dt][qf] = __builtin_amdgcn_mfma_f32_16x16x32_bf16(vf1, pf[qf][1], o[dt][qf], 0, 0, 0);
        }
      }
      __builtin_amdgcn_s_setprio(0);
    }
    __syncthreads();
  }

  #pragma unroll
  for (int qf = 0; qf < 2; ++qf) {
    float lt = lsum[qf];
    lt += __shfl_xor(lt, 16);
    lt += __shfl_xor(lt, 32);
    float inv = 1.f / lt;
    ushort* orow = out + (size_t)(b * TT + qg0 + qf * 16 + li) * DD + h * HDIM;
    #pragma unroll
    for (int dt = 0; dt < 4; ++dt)
      #pragma unroll
      for (int r = 0; r < 4; ++r)
        orow[dt * 16 + g * 4 + r] = f2bf_hw(o[dt][qf][r] * inv);
  }
}

extern "C" void kernel_launch(void* const* d_in, const int* in_sizes, int n_in,
                              void* d_out, int out_size, void* d_ws, size_t ws_size,
                              hipStream_t stream) {
  const float* x     = (const float*)d_in[0];
  const float* W_qkv = (const float*)d_in[1];
  const float* b_qkv = (const float*)d_in[2];
  const float* W_out = (const float*)d_in[3];
  const float* b_out = (const float*)d_in[4];
  float* out = (float*)d_out;

  ushort* x_bf   = (ushort*)d_ws;                   // 8192*1024
  ushort* wtq    = x_bf + (size_t)BT * DD;          // 3072*1024
  ushort* wto    = wtq + (size_t)D3 * DD;           // 1024*1024
  ushort* qkv_bf = wto + (size_t)DD * DD;           // 8192*3072
  ushort* att_bf = qkv_bf + (size_t)BT * D3;        // 8192*1024

  cvt_bf16<<<2048, 256, 0, stream>>>(x, x_bf, BT * DD / 4);
  transpose_cvt<<<dim3(D3 / 64, DD / 64), 256, 0, stream>>>(W_qkv, wtq, DD, D3);
  transpose_cvt<<<dim3(DD / 64, DD / 64), 256, 0, stream>>>(W_out, wto, DD, DD);

  gemm_bt<false><<<dim3(D3 / 128, BT / 128), 256, 0, stream>>>(x_bf, wtq, b_qkv, (void*)qkv_bf, D3);
  attn_mfma<<<dim3(64 * (TT / 128)), 256, 0, stream>>>(qkv_bf, att_bf);
  gemm_bt<true><<<dim3(DD / 128, BT / 128), 256, 0, stream>>>(att_bf, wto, b_out, (void*)out, DD);
}